// Round 1
// baseline (4312.333 us; speedup 1.0000x reference)
//
#include <hip/hip_runtime.h>
#include <hip/hip_bf16.h>
#include <math.h>

// Problem constants (B,T,H,V) = (2,1024,4096,32000)
#define TT 1024
#define MM 2048      // B*T tokens
#define HH 4096
#define VV 32000
#define BETA_ 0.1f
#define NPB (VV/64)  // 500 partial (max,sumexp) blocks per token row

#define BM 128
#define BN 128
#define BK 64

typedef short short8 __attribute__((ext_vector_type(8)));
typedef float f32x4 __attribute__((ext_vector_type(4)));

__device__ inline unsigned f2bf1(float f) {
    union { float f; unsigned u; } v; v.f = f;
    return (v.u + 0x7fffu + ((v.u >> 16) & 1u)) >> 16;   // RNE f32->bf16
}
__device__ inline uint2 pack4(float4 a) {
    uint2 r;
    r.x = f2bf1(a.x) | (f2bf1(a.y) << 16);
    r.y = f2bf1(a.z) | (f2bf1(a.w) << 16);
    return r;
}

// Fused logits GEMM + per-(token, 64-vocab-block) online (max, sumexp) partials.
// X: MM x HH fp32 (tokens), Wt: VV x HH fp32 (vocab rows = B^T layout).
__global__ __launch_bounds__(256) void kto_logits_lse(
    const float* __restrict__ X, const float* __restrict__ Wt,
    float2* __restrict__ part)
{
    __shared__ __align__(16) unsigned char lds[(BM + BN) * BK * 2];
    unsigned char* ldsA = lds;                    // [128][128B] swizzled bf16
    unsigned char* ldsB = lds + BM * BK * 2;

    const int tid    = threadIdx.x;
    const int tile_m = blockIdx.x * BM;           // m-tile fast => W panel LLC reuse
    const int tile_n = blockIdx.y * BN;
    const int srow   = tid >> 1;                  // staging row 0..127
    const int shalf  = tid & 1;                   // staging half (32 floats)
    const int lane   = tid & 63;
    const int wave   = tid >> 6;
    const int wm     = (wave >> 1) * 64;
    const int wn     = (wave & 1) * 64;
    const int lrow   = lane & 15;
    const int lgrp   = lane >> 4;

    f32x4 acc[4][4];
#pragma unroll
    for (int i = 0; i < 4; ++i)
#pragma unroll
        for (int j = 0; j < 4; ++j) acc[i][j] = f32x4{0.f, 0.f, 0.f, 0.f};

    const float4* gA = (const float4*)(X  + (size_t)(tile_m + srow) * HH) + shalf * 8;
    const float4* gB = (const float4*)(Wt + (size_t)(tile_n + srow) * HH) + shalf * 8;
    const int swz = (srow & 7) << 4;

    for (int k0 = 0; k0 < HH; k0 += BK) {
        float4 a[8], b[8];
#pragma unroll
        for (int j = 0; j < 8; ++j) a[j] = gA[j];
#pragma unroll
        for (int j = 0; j < 8; ++j) b[j] = gB[j];
        gA += BK / 4; gB += BK / 4;

        __syncthreads();   // prev iter's ds_reads done before overwrite
#pragma unroll
        for (int j = 0; j < 4; ++j) {
            uint2 lo = pack4(a[2*j]), hi = pack4(a[2*j+1]);
            uint4 qa = make_uint4(lo.x, lo.y, hi.x, hi.y);
            lo = pack4(b[2*j]); hi = pack4(b[2*j+1]);
            uint4 qb = make_uint4(lo.x, lo.y, hi.x, hi.y);
            int kb = shalf * 64 + 16 * j;
            *(uint4*)(ldsA + srow * 128 + (kb ^ swz)) = qa;
            *(uint4*)(ldsB + srow * 128 + (kb ^ swz)) = qb;
        }
        __syncthreads();

#pragma unroll
        for (int kk = 0; kk < 2; ++kk) {
            short8 af[4], bf[4];
#pragma unroll
            for (int mi = 0; mi < 4; ++mi) {
                int r = wm + mi * 16 + lrow;
                af[mi] = *(const short8*)(ldsA + r * 128 + ((kk * 64 + lgrp * 16) ^ ((r & 7) << 4)));
            }
#pragma unroll
            for (int ni = 0; ni < 4; ++ni) {
                int r = wn + ni * 16 + lrow;
                bf[ni] = *(const short8*)(ldsB + r * 128 + ((kk * 64 + lgrp * 16) ^ ((r & 7) << 4)));
            }
#pragma unroll
            for (int mi = 0; mi < 4; ++mi)
#pragma unroll
                for (int ni = 0; ni < 4; ++ni)
                    acc[mi][ni] = __builtin_amdgcn_mfma_f32_16x16x32_bf16(af[mi], bf[ni], acc[mi][ni], 0, 0, 0);
        }
    }

    // Epilogue: per token row, (max, sumexp) over this wave's 64 vocab cols.
    // C/D layout: col = lane&15, row = (lane>>4)*4 + reg  [m89/m91]
    const int nb = blockIdx.y * 2 + (wave & 1);
#pragma unroll
    for (int mi = 0; mi < 4; ++mi) {
#pragma unroll
        for (int r = 0; r < 4; ++r) {
            float v0 = acc[mi][0][r], v1 = acc[mi][1][r], v2 = acc[mi][2][r], v3 = acc[mi][3][r];
            float mx = fmaxf(fmaxf(v0, v1), fmaxf(v2, v3));
#pragma unroll
            for (int d = 1; d < 16; d <<= 1) mx = fmaxf(mx, __shfl_xor(mx, d, 64));
            float s = __expf(v0 - mx) + __expf(v1 - mx) + __expf(v2 - mx) + __expf(v3 - mx);
#pragma unroll
            for (int d = 1; d < 16; d <<= 1) s += __shfl_xor(s, d, 64);
            if (lrow == 0) {
                int rowg = tile_m + wm + mi * 16 + lgrp * 4 + r;
                part[(size_t)rowg * NPB + nb] = make_float2(mx, s);
            }
        }
    }
}

// Target logit per token: fp32 dot(x_t, W[y_t]) for both models.
__global__ __launch_bounds__(256) void kto_target(
    const float* __restrict__ X, const float* __restrict__ RX,
    const float* __restrict__ W, const float* __restrict__ RW,
    const int* __restrict__ Y,
    float* __restrict__ tgtP, float* __restrict__ tgtR)
{
    __shared__ float red[2][4];
    const int t = blockIdx.x;
    int yt = Y[t]; yt = yt < 0 ? 0 : (yt > VV - 1 ? VV - 1 : yt);
    const float4* x4  = (const float4*)(X  + (size_t)t  * HH);
    const float4* rx4 = (const float4*)(RX + (size_t)t  * HH);
    const float4* w4  = (const float4*)(W  + (size_t)yt * HH);
    const float4* rw4 = (const float4*)(RW + (size_t)yt * HH);
    float sp = 0.f, sr = 0.f;
    for (int i = threadIdx.x; i < HH / 4; i += 256) {
        float4 a = x4[i],  w = w4[i];
        sp += a.x * w.x + a.y * w.y + a.z * w.z + a.w * w.w;
        float4 bq = rx4[i], rw = rw4[i];
        sr += bq.x * rw.x + bq.y * rw.y + bq.z * rw.z + bq.w * rw.w;
    }
#pragma unroll
    for (int d = 1; d < 64; d <<= 1) { sp += __shfl_xor(sp, d, 64); sr += __shfl_xor(sr, d, 64); }
    int wv = threadIdx.x >> 6, ln = threadIdx.x & 63;
    if (ln == 0) { red[0][wv] = sp; red[1][wv] = sr; }
    __syncthreads();
    if (threadIdx.x == 0) {
        tgtP[t] = red[0][0] + red[0][1] + red[0][2] + red[0][3];
        tgtR[t] = red[1][0] + red[1][1] + red[1][2] + red[1][3];
    }
}

__device__ inline float2 mrg(float2 a, float2 b) {
    if (b.x == -INFINITY) return a;
    if (a.x == -INFINITY) return b;
    if (a.x >= b.x) { a.y += b.y * __expf(b.x - a.x); return a; }
    b.y += a.y * __expf(a.x - b.x); return b;
}

// Combine 500 partials per token -> lse -> tok_logp = tgt - lse.
__global__ __launch_bounds__(256) void kto_lse_combine(
    const float2* __restrict__ partP, const float2* __restrict__ partR,
    const float* __restrict__ tgtP, const float* __restrict__ tgtR,
    float* __restrict__ tokP, float* __restrict__ tokR)
{
    __shared__ float2 redP[4], redR[4];
    const int t = blockIdx.x;
    float2 ap = make_float2(-INFINITY, 0.f), ar = ap;
    for (int i = threadIdx.x; i < NPB; i += 256) {
        ap = mrg(ap, partP[(size_t)t * NPB + i]);
        ar = mrg(ar, partR[(size_t)t * NPB + i]);
    }
#pragma unroll
    for (int d = 1; d < 64; d <<= 1) {
        float2 o;
        o.x = __shfl_xor(ap.x, d, 64); o.y = __shfl_xor(ap.y, d, 64); ap = mrg(ap, o);
        o.x = __shfl_xor(ar.x, d, 64); o.y = __shfl_xor(ar.y, d, 64); ar = mrg(ar, o);
    }
    int wv = threadIdx.x >> 6, ln = threadIdx.x & 63;
    if (ln == 0) { redP[wv] = ap; redR[wv] = ar; }
    __syncthreads();
    if (threadIdx.x == 0) {
        float2 p = mrg(mrg(redP[0], redP[1]), mrg(redP[2], redP[3]));
        float2 r = mrg(mrg(redR[0], redR[1]), mrg(redR[2], redR[3]));
        tokP[t] = tgtP[t] - (p.x + logf(p.y));
        tokR[t] = tgtR[t] - (r.x + logf(r.y));
    }
}

// Per-sequence means + KTO loss -> scalar.
__global__ __launch_bounds__(1024) void kto_final(
    const float* __restrict__ tokP, const float* __restrict__ tokR,
    const int* __restrict__ Y, const unsigned char* __restrict__ pref,
    float* __restrict__ out)
{
    __shared__ float red[6][16];
    const int t = threadIdx.x;  // 0..1023
    float m0 = (Y[t]      != -100) ? 1.f : 0.f;
    float m1 = (Y[TT + t] != -100) ? 1.f : 0.f;
    float v[6];
    v[0] = m0 * tokP[t];       v[1] = m0 * tokR[t];       v[2] = m0;
    v[3] = m1 * tokP[TT + t];  v[4] = m1 * tokR[TT + t];  v[5] = m1;
#pragma unroll
    for (int d = 1; d < 64; d <<= 1)
#pragma unroll
        for (int j = 0; j < 6; ++j) v[j] += __shfl_xor(v[j], d, 64);
    int wv = threadIdx.x >> 6, ln = threadIdx.x & 63;
    if (ln == 0)
#pragma unroll
        for (int j = 0; j < 6; ++j) red[j][wv] = v[j];
    __syncthreads();
    if (t == 0) {
        float s[6];
#pragma unroll
        for (int j = 0; j < 6; ++j) { s[j] = 0.f; for (int w = 0; w < 16; ++w) s[j] += red[j][w]; }
        // preference_labels: robust to bool-byte or int32 storage
        bool byteStorage = ((pref[1] | pref[2] | pref[3]) != 0) || (pref[4] > 1) ||
                           ((pref[5] | pref[6] | pref[7]) != 0);
        int l0, l1;
        if (byteStorage) { l0 = pref[0]; l1 = pref[1]; }
        else { l0 = ((const int*)pref)[0]; l1 = ((const int*)pref)[1]; }
        float pl0 = s[0] / fmaxf(s[2], 1.f);
        float rl0 = s[1] / fmaxf(s[2], 1.f);
        float pl1 = s[3] / fmaxf(s[5], 1.f);
        float rl1 = s[4] / fmaxf(s[5], 1.f);
        float lr0 = pl0 - rl0, lr1 = pl1 - rl1;
        float mu0 = l0 ? 1.f : -1.f;
        float mu1 = l1 ? 1.f : -1.f;
        float loss0 = 1.f - 1.f / (1.f + expf(-BETA_ * lr0 * mu0));
        float loss1 = 1.f - 1.f / (1.f + expf(-BETA_ * lr1 * mu1));
        out[0] = 0.5f * (loss0 + loss1);
    }
}

extern "C" void kernel_launch(void* const* d_in, const int* in_sizes, int n_in,
                              void* d_out, int out_size, void* d_ws, size_t ws_size,
                              hipStream_t stream) {
    const float* X  = (const float*)d_in[0];
    const float* RX = (const float*)d_in[1];
    const int*   Y  = (const int*)d_in[2];
    const unsigned char* PL = (const unsigned char*)d_in[3];
    const float* W  = (const float*)d_in[4];
    const float* RW = (const float*)d_in[5];
    float* out = (float*)d_out;

    float2* partP = (float2*)d_ws;
    float2* partR = partP + (size_t)MM * NPB;
    float*  tgtP  = (float*)(partR + (size_t)MM * NPB);
    float*  tgtR  = tgtP + MM;
    float*  tokP  = tgtR + MM;
    float*  tokR  = tokP + MM;

    dim3 ggrid(MM / BM, VV / BN);  // (16, 250): m fast-varying for W LLC reuse
    kto_logits_lse<<<ggrid, 256, 0, stream>>>(X,  W,  partP);
    kto_logits_lse<<<ggrid, 256, 0, stream>>>(RX, RW, partR);
    kto_target<<<MM, 256, 0, stream>>>(X, RX, W, RW, Y, tgtP, tgtR);
    kto_lse_combine<<<MM, 256, 0, stream>>>(partP, partR, tgtP, tgtR, tokP, tokR);
    kto_final<<<1, 1024, 0, stream>>>(tokP, tokR, Y, PL, out);
}

// Round 2
// 1889.715 us; speedup vs baseline: 2.2820x; 2.2820x over previous
//
#include <hip/hip_runtime.h>
#include <hip/hip_bf16.h>
#include <math.h>

// Problem constants (B,T,H,V) = (2,1024,4096,32000)
#define TT 1024
#define MM 2048      // B*T tokens
#define HH 4096
#define VV 32000
#define BETA_ 0.1f
#define NPB (VV/64)  // 500 partial (max,sumexp) blocks per token row

#define BM 128
#define BN 128
#define BK 64

typedef short short8 __attribute__((ext_vector_type(8)));
typedef float f32x4 __attribute__((ext_vector_type(4)));

__device__ inline unsigned f2bf1(float f) {
    union { float f; unsigned u; } v; v.f = f;
    return (v.u + 0x7fffu + ((v.u >> 16) & 1u)) >> 16;   // RNE f32->bf16
}
__device__ inline uint2 pack4(float4 a) {
    uint2 r;
    r.x = f2bf1(a.x) | (f2bf1(a.y) << 16);
    r.y = f2bf1(a.z) | (f2bf1(a.w) << 16);
    return r;
}

// global -> LDS direct copy, 16B per lane. LDS dest is wave-uniform base + lane*16.
__device__ __forceinline__ void gload_lds16(const void* g, void* l) {
    __builtin_amdgcn_global_load_lds(
        (const __attribute__((address_space(1))) void*)(uintptr_t)g,
        (__attribute__((address_space(3))) void*)(unsigned)(uintptr_t)l,
        16, 0, 0);
}

// ---------------- fp32 -> bf16 pre-conversion (8 elem / thread / iter) ------
__global__ __launch_bounds__(256) void conv_bf16(
    const float* __restrict__ src, unsigned short* __restrict__ dst, int n8)
{
    int i = blockIdx.x * 256 + threadIdx.x;
    const int stride = gridDim.x * 256;
    for (; i < n8; i += stride) {
        const float4* s = (const float4*)src + 2 * (size_t)i;
        float4 a = s[0], b = s[1];
        uint2 lo = pack4(a), hi = pack4(b);
        *(uint4*)(dst + (size_t)i * 8) = make_uint4(lo.x, lo.y, hi.x, hi.y);
    }
}

// ---------------- bf16 GEMM (m97 structure) + fused online-LSE partials -----
// Xb: MM x HH bf16, Wb: VV x HH bf16 (vocab rows = B^T layout).
__global__ __launch_bounds__(256) void kto_logits_lse_bf16(
    const unsigned short* __restrict__ Xb, const unsigned short* __restrict__ Wb,
    float2* __restrict__ part)
{
    __shared__ __align__(16) unsigned short ldsA[BM * BK];
    __shared__ __align__(16) unsigned short ldsB[BN * BK];

    const int tid    = threadIdx.x;
    const int tile_m = blockIdx.x * BM;           // m-tile fast => W panel LLC reuse
    const int tile_n = blockIdx.y * BN;
    const int lane   = tid & 63;
    const int wave   = tid >> 6;
    const int wm     = (wave >> 1) * 64;
    const int wn     = (wave & 1) * 64;
    const int lrow   = lane & 15;
    const int lgrp   = lane >> 4;

    f32x4 acc[4][4];
#pragma unroll
    for (int i = 0; i < 4; ++i)
#pragma unroll
        for (int j = 0; j < 4; ++j) acc[i][j] = f32x4{0.f, 0.f, 0.f, 0.f};

    // Staging geometry: per K-step each wave copies 32 rows of A and B in
    // 4 chunks of 8 rows (1 KiB per chunk: lane l -> row base+l/8, col (l&7)*8).
    const int srow = wave * 32 + (lane >> 3);
    const int scol = (lane & 7) * 8;
    const unsigned short* gA = Xb + (size_t)(tile_m + srow) * HH + scol;
    const unsigned short* gB = Wb + (size_t)(tile_n + srow) * HH + scol;

    for (int k0 = 0; k0 < HH; k0 += BK) {
#pragma unroll
        for (int c = 0; c < 4; ++c)
            gload_lds16(gA + (size_t)c * (8 * HH) + k0,
                        ldsA + (wave * 32 + c * 8) * BK);
#pragma unroll
        for (int c = 0; c < 4; ++c)
            gload_lds16(gB + (size_t)c * (8 * HH) + k0,
                        ldsB + (wave * 32 + c * 8) * BK);
        __syncthreads();   // compiler drains vmcnt before barrier: LDS ready

#pragma unroll
        for (int kk = 0; kk < 2; ++kk) {
            short8 af[4], bf[4];
#pragma unroll
            for (int mi = 0; mi < 4; ++mi)
                af[mi] = *(const short8*)(ldsA + (wm + mi * 16 + lrow) * BK + kk * 32 + lgrp * 8);
#pragma unroll
            for (int ni = 0; ni < 4; ++ni)
                bf[ni] = *(const short8*)(ldsB + (wn + ni * 16 + lrow) * BK + kk * 32 + lgrp * 8);
#pragma unroll
            for (int mi = 0; mi < 4; ++mi)
#pragma unroll
                for (int ni = 0; ni < 4; ++ni)
                    acc[mi][ni] = __builtin_amdgcn_mfma_f32_16x16x32_bf16(af[mi], bf[ni], acc[mi][ni], 0, 0, 0);
        }
        __syncthreads();   // reads done before next stage overwrites
    }

    // Epilogue: per token row, (max, sumexp) over this wave's 64 vocab cols.
    // C/D layout: col = lane&15, row = (lane>>4)*4 + reg  [m89/m91]
    const int nb = blockIdx.y * 2 + (wave & 1);
#pragma unroll
    for (int mi = 0; mi < 4; ++mi) {
#pragma unroll
        for (int r = 0; r < 4; ++r) {
            float v0 = acc[mi][0][r], v1 = acc[mi][1][r], v2 = acc[mi][2][r], v3 = acc[mi][3][r];
            float mx = fmaxf(fmaxf(v0, v1), fmaxf(v2, v3));
#pragma unroll
            for (int d = 1; d < 16; d <<= 1) mx = fmaxf(mx, __shfl_xor(mx, d, 64));
            float s = __expf(v0 - mx) + __expf(v1 - mx) + __expf(v2 - mx) + __expf(v3 - mx);
#pragma unroll
            for (int d = 1; d < 16; d <<= 1) s += __shfl_xor(s, d, 64);
            if (lrow == 0) {
                int rowg = tile_m + wm + mi * 16 + lgrp * 4 + r;
                part[(size_t)rowg * NPB + nb] = make_float2(mx, s);
            }
        }
    }
}

// ---------------- fallback: round-1 fused fp32 reg-staged GEMM --------------
__global__ __launch_bounds__(256) void kto_logits_lse(
    const float* __restrict__ X, const float* __restrict__ Wt,
    float2* __restrict__ part)
{
    __shared__ __align__(16) unsigned char lds[(BM + BN) * BK * 2];
    unsigned char* ldsA = lds;
    unsigned char* ldsB = lds + BM * BK * 2;

    const int tid    = threadIdx.x;
    const int tile_m = blockIdx.x * BM;
    const int tile_n = blockIdx.y * BN;
    const int srow   = tid >> 1;
    const int shalf  = tid & 1;
    const int lane   = tid & 63;
    const int wave   = tid >> 6;
    const int wm     = (wave >> 1) * 64;
    const int wn     = (wave & 1) * 64;
    const int lrow   = lane & 15;
    const int lgrp   = lane >> 4;

    f32x4 acc[4][4];
#pragma unroll
    for (int i = 0; i < 4; ++i)
#pragma unroll
        for (int j = 0; j < 4; ++j) acc[i][j] = f32x4{0.f, 0.f, 0.f, 0.f};

    const float4* gA = (const float4*)(X  + (size_t)(tile_m + srow) * HH) + shalf * 8;
    const float4* gB = (const float4*)(Wt + (size_t)(tile_n + srow) * HH) + shalf * 8;
    const int swz = (srow & 7) << 4;

    for (int k0 = 0; k0 < HH; k0 += BK) {
        float4 a[8], b[8];
#pragma unroll
        for (int j = 0; j < 8; ++j) a[j] = gA[j];
#pragma unroll
        for (int j = 0; j < 8; ++j) b[j] = gB[j];
        gA += BK / 4; gB += BK / 4;

        __syncthreads();
#pragma unroll
        for (int j = 0; j < 4; ++j) {
            uint2 lo = pack4(a[2*j]), hi = pack4(a[2*j+1]);
            uint4 qa = make_uint4(lo.x, lo.y, hi.x, hi.y);
            lo = pack4(b[2*j]); hi = pack4(b[2*j+1]);
            uint4 qb = make_uint4(lo.x, lo.y, hi.x, hi.y);
            int kb = shalf * 64 + 16 * j;
            *(uint4*)(ldsA + srow * 128 + (kb ^ swz)) = qa;
            *(uint4*)(ldsB + srow * 128 + (kb ^ swz)) = qb;
        }
        __syncthreads();

#pragma unroll
        for (int kk = 0; kk < 2; ++kk) {
            short8 af[4], bf[4];
#pragma unroll
            for (int mi = 0; mi < 4; ++mi) {
                int r = wm + mi * 16 + lrow;
                af[mi] = *(const short8*)(ldsA + r * 128 + ((kk * 64 + lgrp * 16) ^ ((r & 7) << 4)));
            }
#pragma unroll
            for (int ni = 0; ni < 4; ++ni) {
                int r = wn + ni * 16 + lrow;
                bf[ni] = *(const short8*)(ldsB + r * 128 + ((kk * 64 + lgrp * 16) ^ ((r & 7) << 4)));
            }
#pragma unroll
            for (int mi = 0; mi < 4; ++mi)
#pragma unroll
                for (int ni = 0; ni < 4; ++ni)
                    acc[mi][ni] = __builtin_amdgcn_mfma_f32_16x16x32_bf16(af[mi], bf[ni], acc[mi][ni], 0, 0, 0);
        }
    }

    const int nb = blockIdx.y * 2 + (wave & 1);
#pragma unroll
    for (int mi = 0; mi < 4; ++mi) {
#pragma unroll
        for (int r = 0; r < 4; ++r) {
            float v0 = acc[mi][0][r], v1 = acc[mi][1][r], v2 = acc[mi][2][r], v3 = acc[mi][3][r];
            float mx = fmaxf(fmaxf(v0, v1), fmaxf(v2, v3));
#pragma unroll
            for (int d = 1; d < 16; d <<= 1) mx = fmaxf(mx, __shfl_xor(mx, d, 64));
            float s = __expf(v0 - mx) + __expf(v1 - mx) + __expf(v2 - mx) + __expf(v3 - mx);
#pragma unroll
            for (int d = 1; d < 16; d <<= 1) s += __shfl_xor(s, d, 64);
            if (lrow == 0) {
                int rowg = tile_m + wm + mi * 16 + lgrp * 4 + r;
                part[(size_t)rowg * NPB + nb] = make_float2(mx, s);
            }
        }
    }
}

// ---------------- target logit per token (fp32 exact) -----------------------
__global__ __launch_bounds__(256) void kto_target(
    const float* __restrict__ X, const float* __restrict__ RX,
    const float* __restrict__ W, const float* __restrict__ RW,
    const int* __restrict__ Y,
    float* __restrict__ tgtP, float* __restrict__ tgtR)
{
    __shared__ float red[2][4];
    const int t = blockIdx.x;
    int yt = Y[t]; yt = yt < 0 ? 0 : (yt > VV - 1 ? VV - 1 : yt);
    const float4* x4  = (const float4*)(X  + (size_t)t  * HH);
    const float4* rx4 = (const float4*)(RX + (size_t)t  * HH);
    const float4* w4  = (const float4*)(W  + (size_t)yt * HH);
    const float4* rw4 = (const float4*)(RW + (size_t)yt * HH);
    float sp = 0.f, sr = 0.f;
    for (int i = threadIdx.x; i < HH / 4; i += 256) {
        float4 a = x4[i],  w = w4[i];
        sp += a.x * w.x + a.y * w.y + a.z * w.z + a.w * w.w;
        float4 bq = rx4[i], rw = rw4[i];
        sr += bq.x * rw.x + bq.y * rw.y + bq.z * rw.z + bq.w * rw.w;
    }
#pragma unroll
    for (int d = 1; d < 64; d <<= 1) { sp += __shfl_xor(sp, d, 64); sr += __shfl_xor(sr, d, 64); }
    int wv = threadIdx.x >> 6, ln = threadIdx.x & 63;
    if (ln == 0) { red[0][wv] = sp; red[1][wv] = sr; }
    __syncthreads();
    if (threadIdx.x == 0) {
        tgtP[t] = red[0][0] + red[0][1] + red[0][2] + red[0][3];
        tgtR[t] = red[1][0] + red[1][1] + red[1][2] + red[1][3];
    }
}

__device__ inline float2 mrg(float2 a, float2 b) {
    if (b.x == -INFINITY) return a;
    if (a.x == -INFINITY) return b;
    if (a.x >= b.x) { a.y += b.y * __expf(b.x - a.x); return a; }
    b.y += a.y * __expf(a.x - b.x); return b;
}

__global__ __launch_bounds__(256) void kto_lse_combine(
    const float2* __restrict__ partP, const float2* __restrict__ partR,
    const float* __restrict__ tgtP, const float* __restrict__ tgtR,
    float* __restrict__ tokP, float* __restrict__ tokR)
{
    __shared__ float2 redP[4], redR[4];
    const int t = blockIdx.x;
    float2 ap = make_float2(-INFINITY, 0.f), ar = ap;
    for (int i = threadIdx.x; i < NPB; i += 256) {
        ap = mrg(ap, partP[(size_t)t * NPB + i]);
        ar = mrg(ar, partR[(size_t)t * NPB + i]);
    }
#pragma unroll
    for (int d = 1; d < 64; d <<= 1) {
        float2 o;
        o.x = __shfl_xor(ap.x, d, 64); o.y = __shfl_xor(ap.y, d, 64); ap = mrg(ap, o);
        o.x = __shfl_xor(ar.x, d, 64); o.y = __shfl_xor(ar.y, d, 64); ar = mrg(ar, o);
    }
    int wv = threadIdx.x >> 6, ln = threadIdx.x & 63;
    if (ln == 0) { redP[wv] = ap; redR[wv] = ar; }
    __syncthreads();
    if (threadIdx.x == 0) {
        float2 p = mrg(mrg(redP[0], redP[1]), mrg(redP[2], redP[3]));
        float2 r = mrg(mrg(redR[0], redR[1]), mrg(redR[2], redR[3]));
        tokP[t] = tgtP[t] - (p.x + logf(p.y));
        tokR[t] = tgtR[t] - (r.x + logf(r.y));
    }
}

__global__ __launch_bounds__(1024) void kto_final(
    const float* __restrict__ tokP, const float* __restrict__ tokR,
    const int* __restrict__ Y, const unsigned char* __restrict__ pref,
    float* __restrict__ out)
{
    __shared__ float red[6][16];
    const int t = threadIdx.x;  // 0..1023
    float m0 = (Y[t]      != -100) ? 1.f : 0.f;
    float m1 = (Y[TT + t] != -100) ? 1.f : 0.f;
    float v[6];
    v[0] = m0 * tokP[t];       v[1] = m0 * tokR[t];       v[2] = m0;
    v[3] = m1 * tokP[TT + t];  v[4] = m1 * tokR[TT + t];  v[5] = m1;
#pragma unroll
    for (int d = 1; d < 64; d <<= 1)
#pragma unroll
        for (int j = 0; j < 6; ++j) v[j] += __shfl_xor(v[j], d, 64);
    int wv = threadIdx.x >> 6, ln = threadIdx.x & 63;
    if (ln == 0)
#pragma unroll
        for (int j = 0; j < 6; ++j) red[j][wv] = v[j];
    __syncthreads();
    if (t == 0) {
        float s[6];
#pragma unroll
        for (int j = 0; j < 6; ++j) { s[j] = 0.f; for (int w = 0; w < 16; ++w) s[j] += red[j][w]; }
        bool byteStorage = ((pref[1] | pref[2] | pref[3]) != 0) || (pref[4] > 1) ||
                           ((pref[5] | pref[6] | pref[7]) != 0);
        int l0, l1;
        if (byteStorage) { l0 = pref[0]; l1 = pref[1]; }
        else { l0 = ((const int*)pref)[0]; l1 = ((const int*)pref)[1]; }
        float pl0 = s[0] / fmaxf(s[2], 1.f);
        float rl0 = s[1] / fmaxf(s[2], 1.f);
        float pl1 = s[3] / fmaxf(s[5], 1.f);
        float rl1 = s[4] / fmaxf(s[5], 1.f);
        float lr0 = pl0 - rl0, lr1 = pl1 - rl1;
        float mu0 = l0 ? 1.f : -1.f;
        float mu1 = l1 ? 1.f : -1.f;
        float loss0 = 1.f - 1.f / (1.f + expf(-BETA_ * lr0 * mu0));
        float loss1 = 1.f - 1.f / (1.f + expf(-BETA_ * lr1 * mu1));
        out[0] = 0.5f * (loss0 + loss1);
    }
}

extern "C" void kernel_launch(void* const* d_in, const int* in_sizes, int n_in,
                              void* d_out, int out_size, void* d_ws, size_t ws_size,
                              hipStream_t stream) {
    const float* X  = (const float*)d_in[0];
    const float* RX = (const float*)d_in[1];
    const int*   Y  = (const int*)d_in[2];
    const unsigned char* PL = (const unsigned char*)d_in[3];
    const float* W  = (const float*)d_in[4];
    const float* RW = (const float*)d_in[5];
    float* out = (float*)d_out;

    // ws layout
    char* p = (char*)d_ws;
    float2* partP = (float2*)p;                 p += (size_t)MM * NPB * sizeof(float2);
    float2* partR = (float2*)p;                 p += (size_t)MM * NPB * sizeof(float2);
    float*  tgtP  = (float*)p;                  p += MM * sizeof(float);
    float*  tgtR  = (float*)p;                  p += MM * sizeof(float);
    float*  tokP  = (float*)p;                  p += MM * sizeof(float);
    float*  tokR  = (float*)p;                  p += MM * sizeof(float);
    unsigned short* Xbf  = (unsigned short*)p;  p += (size_t)MM * HH * 2;
    unsigned short* RXbf = (unsigned short*)p;  p += (size_t)MM * HH * 2;
    unsigned short* Wbf  = (unsigned short*)p;  p += (size_t)VV * HH * 2;
    const size_t need = (size_t)(p - (char*)d_ws);

    dim3 ggrid(MM / BM, VV / BN);  // (16, 250): m fast-varying for W LLC reuse

    if (ws_size >= need) {
        // fast path: pre-convert to bf16, then global_load_lds GEMMs.
        conv_bf16<<<512,  256, 0, stream>>>(X,  Xbf,  (int)((size_t)MM * HH / 8));
        conv_bf16<<<512,  256, 0, stream>>>(RX, RXbf, (int)((size_t)MM * HH / 8));
        conv_bf16<<<2048, 256, 0, stream>>>(W,  Wbf,  (int)((size_t)VV * HH / 8));
        kto_logits_lse_bf16<<<ggrid, 256, 0, stream>>>(Xbf, Wbf, partP);
        conv_bf16<<<2048, 256, 0, stream>>>(RW, Wbf,  (int)((size_t)VV * HH / 8));
        kto_logits_lse_bf16<<<ggrid, 256, 0, stream>>>(RXbf, Wbf, partR);
    } else {
        // fallback: fused fp32 reg-staged path (round-1, known-correct)
        kto_logits_lse<<<ggrid, 256, 0, stream>>>(X,  W,  partP);
        kto_logits_lse<<<ggrid, 256, 0, stream>>>(RX, RW, partR);
    }
    kto_target<<<MM, 256, 0, stream>>>(X, RX, W, RW, Y, tgtP, tgtR);
    kto_lse_combine<<<MM, 256, 0, stream>>>(partP, partR, tgtP, tgtR, tokP, tokR);
    kto_final<<<1, 1024, 0, stream>>>(tokP, tokR, Y, PL, out);
}

// Round 3
// 1647.293 us; speedup vs baseline: 2.6178x; 1.1472x over previous
//
#include <hip/hip_runtime.h>
#include <hip/hip_bf16.h>
#include <math.h>

// Problem constants (B,T,H,V) = (2,1024,4096,32000)
#define TT 1024
#define MM 2048      // B*T tokens
#define HH 4096
#define VV 32000
#define BETA_ 0.1f
#define NPB (VV/64)  // 500 partial (max,sumexp) blocks per token row

#define BM 128
#define BN 128
#define BK 64

typedef short short8 __attribute__((ext_vector_type(8)));
typedef float f32x4 __attribute__((ext_vector_type(4)));

__device__ inline unsigned f2bf1(float f) {
    union { float f; unsigned u; } v; v.f = f;
    return (v.u + 0x7fffu + ((v.u >> 16) & 1u)) >> 16;   // RNE f32->bf16
}
__device__ inline uint2 pack4(float4 a) {
    uint2 r;
    r.x = f2bf1(a.x) | (f2bf1(a.y) << 16);
    r.y = f2bf1(a.z) | (f2bf1(a.w) << 16);
    return r;
}

// global -> LDS direct copy, 16B per lane. LDS dest is wave-uniform base + lane*16.
__device__ __forceinline__ void gload_lds16(const void* g, void* l) {
    __builtin_amdgcn_global_load_lds(
        (const __attribute__((address_space(1))) void*)(uintptr_t)g,
        (__attribute__((address_space(3))) void*)(unsigned)(uintptr_t)l,
        16, 0, 0);
}

// ---------------- fp32 -> bf16 pre-conversion (8 elem / thread / iter) ------
__global__ __launch_bounds__(256) void conv_bf16(
    const float* __restrict__ src, unsigned short* __restrict__ dst, int n8)
{
    int i = blockIdx.x * 256 + threadIdx.x;
    const int stride = gridDim.x * 256;
    for (; i < n8; i += stride) {
        const float4* s = (const float4*)src + 2 * (size_t)i;
        float4 a = s[0], b = s[1];
        uint2 lo = pack4(a), hi = pack4(b);
        *(uint4*)(dst + (size_t)i * 8) = make_uint4(lo.x, lo.y, hi.x, hi.y);
    }
}

// ---------------- bf16 GEMM (m97 structure + T2 swizzle) + fused LSE --------
// Xb: MM x HH bf16, Wb: VV x HH bf16 (vocab rows = B^T layout).
// LDS swizzle (rule #21, both-sides): LDS dest stays linear (global_load_lds
// requirement); the XOR kb^((row&7)<<4) is applied to the per-lane GLOBAL
// source column (lane-constant (lane>>3)<<4 bytes) and to the ds_read addr.
__global__ __launch_bounds__(256) void kto_logits_lse_bf16(
    const unsigned short* __restrict__ Xb, const unsigned short* __restrict__ Wb,
    float2* __restrict__ part)
{
    __shared__ __align__(16) unsigned char ldsA[BM * BK * 2];
    __shared__ __align__(16) unsigned char ldsB[BN * BK * 2];

    const int tid    = threadIdx.x;
    const int tile_m = blockIdx.x * BM;           // m-tile fast => W panel LLC reuse
    const int tile_n = blockIdx.y * BN;
    const int lane   = tid & 63;
    const int wave   = tid >> 6;
    const int wm     = (wave >> 1) * 64;
    const int wn     = (wave & 1) * 64;
    const int lrow   = lane & 15;
    const int lgrp   = lane >> 4;

    f32x4 acc[4][4];
#pragma unroll
    for (int i = 0; i < 4; ++i)
#pragma unroll
        for (int j = 0; j < 4; ++j) acc[i][j] = f32x4{0.f, 0.f, 0.f, 0.f};

    // Staging: per K-step each wave copies 32 rows (4 chunks of 8 rows).
    // Lane l -> row chunkbase + (l>>3), source col ((l&7)*8) ^ ((l>>3)<<3) elems
    // (the XOR pre-applies the LDS swizzle; bijective within the 64-elem row).
    const int srow = wave * 32 + (lane >> 3);
    const int scol = ((lane & 7) * 8) ^ ((lane >> 3) << 3);
    const unsigned short* gA = Xb + (size_t)(tile_m + srow) * HH + scol;
    const unsigned short* gB = Wb + (size_t)(tile_n + srow) * HH + scol;

    for (int k0 = 0; k0 < HH; k0 += BK) {
#pragma unroll
        for (int c = 0; c < 4; ++c)
            gload_lds16(gA + (size_t)c * (8 * HH) + k0,
                        ldsA + (wave * 32 + c * 8) * 128);
#pragma unroll
        for (int c = 0; c < 4; ++c)
            gload_lds16(gB + (size_t)c * (8 * HH) + k0,
                        ldsB + (wave * 32 + c * 8) * 128);
        __syncthreads();   // compiler drains vmcnt before barrier: LDS ready

#pragma unroll
        for (int kk = 0; kk < 2; ++kk) {
            short8 af[4], bf[4];
#pragma unroll
            for (int mi = 0; mi < 4; ++mi) {
                int rr = wm + mi * 16 + lrow;
                af[mi] = *(const short8*)(ldsA + rr * 128 + ((kk * 64 + lgrp * 16) ^ ((rr & 7) << 4)));
            }
#pragma unroll
            for (int ni = 0; ni < 4; ++ni) {
                int rr = wn + ni * 16 + lrow;
                bf[ni] = *(const short8*)(ldsB + rr * 128 + ((kk * 64 + lgrp * 16) ^ ((rr & 7) << 4)));
            }
#pragma unroll
            for (int mi = 0; mi < 4; ++mi)
#pragma unroll
                for (int ni = 0; ni < 4; ++ni)
                    acc[mi][ni] = __builtin_amdgcn_mfma_f32_16x16x32_bf16(af[mi], bf[ni], acc[mi][ni], 0, 0, 0);
        }
        __syncthreads();   // reads done before next stage overwrites
    }

    // Epilogue: per token row, (max, sumexp) over this wave's 64 vocab cols.
    // C/D layout: col = lane&15, row = (lane>>4)*4 + reg  [m89/m91]
    const int nb = blockIdx.y * 2 + (wave & 1);
#pragma unroll
    for (int mi = 0; mi < 4; ++mi) {
#pragma unroll
        for (int r = 0; r < 4; ++r) {
            float v0 = acc[mi][0][r], v1 = acc[mi][1][r], v2 = acc[mi][2][r], v3 = acc[mi][3][r];
            float mx = fmaxf(fmaxf(v0, v1), fmaxf(v2, v3));
#pragma unroll
            for (int d = 1; d < 16; d <<= 1) mx = fmaxf(mx, __shfl_xor(mx, d, 64));
            float s = __expf(v0 - mx) + __expf(v1 - mx) + __expf(v2 - mx) + __expf(v3 - mx);
#pragma unroll
            for (int d = 1; d < 16; d <<= 1) s += __shfl_xor(s, d, 64);
            if (lrow == 0) {
                int rowg = tile_m + wm + mi * 16 + lgrp * 4 + r;
                part[(size_t)rowg * NPB + nb] = make_float2(mx, s);
            }
        }
    }
}

// ---------------- fallback: round-1 fused fp32 reg-staged GEMM --------------
__global__ __launch_bounds__(256) void kto_logits_lse(
    const float* __restrict__ X, const float* __restrict__ Wt,
    float2* __restrict__ part)
{
    __shared__ __align__(16) unsigned char lds[(BM + BN) * BK * 2];
    unsigned char* ldsA = lds;
    unsigned char* ldsB = lds + BM * BK * 2;

    const int tid    = threadIdx.x;
    const int tile_m = blockIdx.x * BM;
    const int tile_n = blockIdx.y * BN;
    const int srow   = tid >> 1;
    const int shalf  = tid & 1;
    const int lane   = tid & 63;
    const int wave   = tid >> 6;
    const int wm     = (wave >> 1) * 64;
    const int wn     = (wave & 1) * 64;
    const int lrow   = lane & 15;
    const int lgrp   = lane >> 4;

    f32x4 acc[4][4];
#pragma unroll
    for (int i = 0; i < 4; ++i)
#pragma unroll
        for (int j = 0; j < 4; ++j) acc[i][j] = f32x4{0.f, 0.f, 0.f, 0.f};

    const float4* gA = (const float4*)(X  + (size_t)(tile_m + srow) * HH) + shalf * 8;
    const float4* gB = (const float4*)(Wt + (size_t)(tile_n + srow) * HH) + shalf * 8;
    const int swz = (srow & 7) << 4;

    for (int k0 = 0; k0 < HH; k0 += BK) {
        float4 a[8], b[8];
#pragma unroll
        for (int j = 0; j < 8; ++j) a[j] = gA[j];
#pragma unroll
        for (int j = 0; j < 8; ++j) b[j] = gB[j];
        gA += BK / 4; gB += BK / 4;

        __syncthreads();
#pragma unroll
        for (int j = 0; j < 4; ++j) {
            uint2 lo = pack4(a[2*j]), hi = pack4(a[2*j+1]);
            uint4 qa = make_uint4(lo.x, lo.y, hi.x, hi.y);
            lo = pack4(b[2*j]); hi = pack4(b[2*j+1]);
            uint4 qb = make_uint4(lo.x, lo.y, hi.x, hi.y);
            int kb = shalf * 64 + 16 * j;
            *(uint4*)(ldsA + srow * 128 + (kb ^ swz)) = qa;
            *(uint4*)(ldsB + srow * 128 + (kb ^ swz)) = qb;
        }
        __syncthreads();

#pragma unroll
        for (int kk = 0; kk < 2; ++kk) {
            short8 af[4], bf[4];
#pragma unroll
            for (int mi = 0; mi < 4; ++mi) {
                int r = wm + mi * 16 + lrow;
                af[mi] = *(const short8*)(ldsA + r * 128 + ((kk * 64 + lgrp * 16) ^ ((r & 7) << 4)));
            }
#pragma unroll
            for (int ni = 0; ni < 4; ++ni) {
                int r = wn + ni * 16 + lrow;
                bf[ni] = *(const short8*)(ldsB + r * 128 + ((kk * 64 + lgrp * 16) ^ ((r & 7) << 4)));
            }
#pragma unroll
            for (int mi = 0; mi < 4; ++mi)
#pragma unroll
                for (int ni = 0; ni < 4; ++ni)
                    acc[mi][ni] = __builtin_amdgcn_mfma_f32_16x16x32_bf16(af[mi], bf[ni], acc[mi][ni], 0, 0, 0);
        }
    }

    const int nb = blockIdx.y * 2 + (wave & 1);
#pragma unroll
    for (int mi = 0; mi < 4; ++mi) {
#pragma unroll
        for (int r = 0; r < 4; ++r) {
            float v0 = acc[mi][0][r], v1 = acc[mi][1][r], v2 = acc[mi][2][r], v3 = acc[mi][3][r];
            float mx = fmaxf(fmaxf(v0, v1), fmaxf(v2, v3));
#pragma unroll
            for (int d = 1; d < 16; d <<= 1) mx = fmaxf(mx, __shfl_xor(mx, d, 64));
            float s = __expf(v0 - mx) + __expf(v1 - mx) + __expf(v2 - mx) + __expf(v3 - mx);
#pragma unroll
            for (int d = 1; d < 16; d <<= 1) s += __shfl_xor(s, d, 64);
            if (lrow == 0) {
                int rowg = tile_m + wm + mi * 16 + lgrp * 4 + r;
                part[(size_t)rowg * NPB + nb] = make_float2(mx, s);
            }
        }
    }
}

// ---------------- target logit per token (fp32 exact) -----------------------
__global__ __launch_bounds__(256) void kto_target(
    const float* __restrict__ X, const float* __restrict__ RX,
    const float* __restrict__ W, const float* __restrict__ RW,
    const int* __restrict__ Y,
    float* __restrict__ tgtP, float* __restrict__ tgtR)
{
    __shared__ float red[2][4];
    const int t = blockIdx.x;
    int yt = Y[t]; yt = yt < 0 ? 0 : (yt > VV - 1 ? VV - 1 : yt);
    const float4* x4  = (const float4*)(X  + (size_t)t  * HH);
    const float4* rx4 = (const float4*)(RX + (size_t)t  * HH);
    const float4* w4  = (const float4*)(W  + (size_t)yt * HH);
    const float4* rw4 = (const float4*)(RW + (size_t)yt * HH);
    float sp = 0.f, sr = 0.f;
    for (int i = threadIdx.x; i < HH / 4; i += 256) {
        float4 a = x4[i],  w = w4[i];
        sp += a.x * w.x + a.y * w.y + a.z * w.z + a.w * w.w;
        float4 bq = rx4[i], rw = rw4[i];
        sr += bq.x * rw.x + bq.y * rw.y + bq.z * rw.z + bq.w * rw.w;
    }
#pragma unroll
    for (int d = 1; d < 64; d <<= 1) { sp += __shfl_xor(sp, d, 64); sr += __shfl_xor(sr, d, 64); }
    int wv = threadIdx.x >> 6, ln = threadIdx.x & 63;
    if (ln == 0) { red[0][wv] = sp; red[1][wv] = sr; }
    __syncthreads();
    if (threadIdx.x == 0) {
        tgtP[t] = red[0][0] + red[0][1] + red[0][2] + red[0][3];
        tgtR[t] = red[1][0] + red[1][1] + red[1][2] + red[1][3];
    }
}

__device__ inline float2 mrg(float2 a, float2 b) {
    if (b.x == -INFINITY) return a;
    if (a.x == -INFINITY) return b;
    if (a.x >= b.x) { a.y += b.y * __expf(b.x - a.x); return a; }
    b.y += a.y * __expf(a.x - b.x); return b;
}

__global__ __launch_bounds__(256) void kto_lse_combine(
    const float2* __restrict__ partP, const float2* __restrict__ partR,
    const float* __restrict__ tgtP, const float* __restrict__ tgtR,
    float* __restrict__ tokP, float* __restrict__ tokR)
{
    __shared__ float2 redP[4], redR[4];
    const int t = blockIdx.x;
    float2 ap = make_float2(-INFINITY, 0.f), ar = ap;
    for (int i = threadIdx.x; i < NPB; i += 256) {
        ap = mrg(ap, partP[(size_t)t * NPB + i]);
        ar = mrg(ar, partR[(size_t)t * NPB + i]);
    }
#pragma unroll
    for (int d = 1; d < 64; d <<= 1) {
        float2 o;
        o.x = __shfl_xor(ap.x, d, 64); o.y = __shfl_xor(ap.y, d, 64); ap = mrg(ap, o);
        o.x = __shfl_xor(ar.x, d, 64); o.y = __shfl_xor(ar.y, d, 64); ar = mrg(ar, o);
    }
    int wv = threadIdx.x >> 6, ln = threadIdx.x & 63;
    if (ln == 0) { redP[wv] = ap; redR[wv] = ar; }
    __syncthreads();
    if (threadIdx.x == 0) {
        float2 p = mrg(mrg(redP[0], redP[1]), mrg(redP[2], redP[3]));
        float2 r = mrg(mrg(redR[0], redR[1]), mrg(redR[2], redR[3]));
        tokP[t] = tgtP[t] - (p.x + logf(p.y));
        tokR[t] = tgtR[t] - (r.x + logf(r.y));
    }
}

__global__ __launch_bounds__(1024) void kto_final(
    const float* __restrict__ tokP, const float* __restrict__ tokR,
    const int* __restrict__ Y, const unsigned char* __restrict__ pref,
    float* __restrict__ out)
{
    __shared__ float red[6][16];
    const int t = threadIdx.x;  // 0..1023
    float m0 = (Y[t]      != -100) ? 1.f : 0.f;
    float m1 = (Y[TT + t] != -100) ? 1.f : 0.f;
    float v[6];
    v[0] = m0 * tokP[t];       v[1] = m0 * tokR[t];       v[2] = m0;
    v[3] = m1 * tokP[TT + t];  v[4] = m1 * tokR[TT + t];  v[5] = m1;
#pragma unroll
    for (int d = 1; d < 64; d <<= 1)
#pragma unroll
        for (int j = 0; j < 6; ++j) v[j] += __shfl_xor(v[j], d, 64);
    int wv = threadIdx.x >> 6, ln = threadIdx.x & 63;
    if (ln == 0)
#pragma unroll
        for (int j = 0; j < 6; ++j) red[j][wv] = v[j];
    __syncthreads();
    if (t == 0) {
        float s[6];
#pragma unroll
        for (int j = 0; j < 6; ++j) { s[j] = 0.f; for (int w = 0; w < 16; ++w) s[j] += red[j][w]; }
        bool byteStorage = ((pref[1] | pref[2] | pref[3]) != 0) || (pref[4] > 1) ||
                           ((pref[5] | pref[6] | pref[7]) != 0);
        int l0, l1;
        if (byteStorage) { l0 = pref[0]; l1 = pref[1]; }
        else { l0 = ((const int*)pref)[0]; l1 = ((const int*)pref)[1]; }
        float pl0 = s[0] / fmaxf(s[2], 1.f);
        float rl0 = s[1] / fmaxf(s[2], 1.f);
        float pl1 = s[3] / fmaxf(s[5], 1.f);
        float rl1 = s[4] / fmaxf(s[5], 1.f);
        float lr0 = pl0 - rl0, lr1 = pl1 - rl1;
        float mu0 = l0 ? 1.f : -1.f;
        float mu1 = l1 ? 1.f : -1.f;
        float loss0 = 1.f - 1.f / (1.f + expf(-BETA_ * lr0 * mu0));
        float loss1 = 1.f - 1.f / (1.f + expf(-BETA_ * lr1 * mu1));
        out[0] = 0.5f * (loss0 + loss1);
    }
}

extern "C" void kernel_launch(void* const* d_in, const int* in_sizes, int n_in,
                              void* d_out, int out_size, void* d_ws, size_t ws_size,
                              hipStream_t stream) {
    const float* X  = (const float*)d_in[0];
    const float* RX = (const float*)d_in[1];
    const int*   Y  = (const int*)d_in[2];
    const unsigned char* PL = (const unsigned char*)d_in[3];
    const float* W  = (const float*)d_in[4];
    const float* RW = (const float*)d_in[5];
    float* out = (float*)d_out;

    // ws layout
    char* p = (char*)d_ws;
    float2* partP = (float2*)p;                 p += (size_t)MM * NPB * sizeof(float2);
    float2* partR = (float2*)p;                 p += (size_t)MM * NPB * sizeof(float2);
    float*  tgtP  = (float*)p;                  p += MM * sizeof(float);
    float*  tgtR  = (float*)p;                  p += MM * sizeof(float);
    float*  tokP  = (float*)p;                  p += MM * sizeof(float);
    float*  tokR  = (float*)p;                  p += MM * sizeof(float);
    unsigned short* Xbf  = (unsigned short*)p;  p += (size_t)MM * HH * 2;
    unsigned short* RXbf = (unsigned short*)p;  p += (size_t)MM * HH * 2;
    unsigned short* Wbf  = (unsigned short*)p;  p += (size_t)VV * HH * 2;
    const size_t need = (size_t)(p - (char*)d_ws);

    dim3 ggrid(MM / BM, VV / BN);  // (16, 250): m fast-varying for W LLC reuse

    if (ws_size >= need) {
        // fast path: pre-convert to bf16, then global_load_lds GEMMs.
        conv_bf16<<<512,  256, 0, stream>>>(X,  Xbf,  (int)((size_t)MM * HH / 8));
        conv_bf16<<<512,  256, 0, stream>>>(RX, RXbf, (int)((size_t)MM * HH / 8));
        conv_bf16<<<2048, 256, 0, stream>>>(W,  Wbf,  (int)((size_t)VV * HH / 8));
        kto_logits_lse_bf16<<<ggrid, 256, 0, stream>>>(Xbf, Wbf, partP);
        conv_bf16<<<2048, 256, 0, stream>>>(RW, Wbf,  (int)((size_t)VV * HH / 8));
        kto_logits_lse_bf16<<<ggrid, 256, 0, stream>>>(RXbf, Wbf, partR);
    } else {
        // fallback: fused fp32 reg-staged path (round-1, known-correct)
        kto_logits_lse<<<ggrid, 256, 0, stream>>>(X,  W,  partP);
        kto_logits_lse<<<ggrid, 256, 0, stream>>>(RX, RW, partR);
    }
    kto_target<<<MM, 256, 0, stream>>>(X, RX, W, RW, Y, tgtP, tgtR);
    kto_lse_combine<<<MM, 256, 0, stream>>>(partP, partR, tgtP, tgtR, tokP, tokR);
    kto_final<<<1, 1024, 0, stream>>>(tokP, tokR, Y, PL, out);
}

// Round 4
// 1213.096 us; speedup vs baseline: 3.5548x; 1.3579x over previous
//
#include <hip/hip_runtime.h>
#include <hip/hip_bf16.h>
#include <math.h>

// Problem constants (B,T,H,V) = (2,1024,4096,32000)
#define TT 1024
#define MM 2048      // B*T tokens
#define HH 4096
#define VV 32000
#define BETA_ 0.1f
#define NPB (VV/64)  // 500 partial (max,sumexp) blocks per token row

// 8-phase GEMM geometry
#define BM 256
#define BN 256
#define BK 64
#define NT (HH/BK)   // 64 K-tiles

typedef short short8 __attribute__((ext_vector_type(8)));
typedef float f32x4 __attribute__((ext_vector_type(4)));

__device__ inline unsigned f2bf1(float f) {
    union { float f; unsigned u; } v; v.f = f;
    return (v.u + 0x7fffu + ((v.u >> 16) & 1u)) >> 16;   // RNE f32->bf16
}
__device__ inline uint2 pack4(float4 a) {
    uint2 r;
    r.x = f2bf1(a.x) | (f2bf1(a.y) << 16);
    r.y = f2bf1(a.z) | (f2bf1(a.w) << 16);
    return r;
}

// global -> LDS direct copy, 16B per lane. LDS dest is wave-uniform base + lane*16.
__device__ __forceinline__ void gload_lds16(const void* g, void* l) {
    __builtin_amdgcn_global_load_lds(
        (const __attribute__((address_space(1))) void*)(uintptr_t)g,
        (__attribute__((address_space(3))) void*)(unsigned)(uintptr_t)l,
        16, 0, 0);
}

// ---------------- fp32 -> bf16 pre-conversion (8 elem / thread / iter) ------
__global__ __launch_bounds__(256) void conv_bf16(
    const float* __restrict__ src, unsigned short* __restrict__ dst, int n8)
{
    int i = blockIdx.x * 256 + threadIdx.x;
    const int stride = gridDim.x * 256;
    for (; i < n8; i += stride) {
        const float4* s = (const float4*)src + 2 * (size_t)i;
        float4 a = s[0], b = s[1];
        uint2 lo = pack4(a), hi = pack4(b);
        *(uint4*)(dst + (size_t)i * 8) = make_uint4(lo.x, lo.y, hi.x, hi.y);
    }
}

// ============ 256x256 8-phase bf16 GEMM (T2+T3+T4+T5) + fused LSE ==========
// Half-tile kinds (s&3): 0=B0,1=B1,2=A0,3=A1. Stage lead = 6 halves.
// Phase plan per K-tile t (buf p=t&1), quadrants (mh,nh):
//   P0 (0,0): read afa(8)+bfa(4); stage s=4t+6 (A0,t+1); vmcnt(6); barrier; MFMA16
//   P1 (0,1): read bfb(4);        stage s=4t+7 (A1,t+1); MFMA16
//   P2 (1,0): read afb(8);        stage s=4t+8 (B0,t+2); MFMA16   [B of t dead @P1 end]
//   P3 (1,1): (regs only);        stage s=4t+9 (B1,t+2); MFMA16   [A of t dead @P2 end]
// Every ds_read is consumed by an MFMA in its own phase, so LDS regions are
// provably dead before the stage that overwrites them (WAR safe); tile t's
// halves (s=4t..4t+3) were issued >=3 phases back, so vmcnt(6) at P0 plus the
// barrier guarantees they landed (RAW safe).
__global__ __launch_bounds__(512, 2) void kto_logits_lse_bf16_8p(
    const unsigned short* __restrict__ Xb, const unsigned short* __restrict__ Wb,
    float2* __restrict__ part)
{
    __shared__ __align__(16) unsigned char lds[131072];  // A: 2x32KB, B: 2x32KB

    const int tid  = threadIdx.x;
    const int lane = tid & 63;
    const int wave = tid >> 6;        // 0..7
    const int wr   = wave >> 2;       // 0..1  (M)
    const int wc   = wave & 3;        // 0..3  (N)
    const int lrow = lane & 15;
    const int lgrp = lane >> 4;

    // XCD-aware bijective swizzle: 1000 wgs, 8 XCDs, chunks of 125, m-fast.
    const int fid  = blockIdx.y * gridDim.x + blockIdx.x;   // 0..999
    const int swz  = (fid & 7) * 125 + (fid >> 3);
    const int tile_m = (swz & 7) * BM;     // 8 m-tiles
    const int tile_n = (swz >> 3) * BN;    // 125 n-tiles

    // Pre-swizzled staging source column (elements), matches ds_read XOR.
    const int scol = ((lane & 7) * 8) ^ ((lane >> 3) << 3);

    f32x4 acc[8][4];
#pragma unroll
    for (int i = 0; i < 8; ++i)
#pragma unroll
        for (int j = 0; j < 4; ++j) acc[i][j] = f32x4{0.f, 0.f, 0.f, 0.f};

#define STAGE_HALF(S)                                                         \
    do { int s_ = (S);                                                        \
        if (s_ < 4 * NT) {                                                    \
            int ts_ = s_ >> 2, kind_ = s_ & 3, buf_ = ts_ & 1;                \
            int isA_ = kind_ >> 1, half_ = kind_ & 1;                         \
            const unsigned short* base_ = isA_                                \
                ? Xb + (size_t)tile_m * HH : Wb + (size_t)tile_n * HH;        \
            unsigned char* lb_ = lds + (isA_ ? 0 : 65536) + buf_ * 32768;     \
            _Pragma("unroll")                                                 \
            for (int c_ = 0; c_ < 2; ++c_) {                                  \
                int rt_ = half_ * 128 + wave * 16 + c_ * 8;                   \
                gload_lds16(base_ + (size_t)(rt_ + (lane >> 3)) * HH          \
                                  + ts_ * 64 + scol,                          \
                            lb_ + rt_ * 128);                                 \
            }                                                                 \
        } } while (0)

#define LOAD_A(DST, MH)                                                       \
    _Pragma("unroll") for (int m_ = 0; m_ < 4; ++m_)                          \
    _Pragma("unroll") for (int kk_ = 0; kk_ < 2; ++kk_) {                     \
        int rr_ = wr * 128 + (MH) * 64 + m_ * 16 + lrow;                      \
        DST[m_][kk_] = *(const short8*)(ldsAp + rr_ * 128 +                   \
            ((kk_ * 64 + lgrp * 16) ^ ((rr_ & 7) << 4))); }

#define LOAD_B(DST, NH)                                                       \
    _Pragma("unroll") for (int n_ = 0; n_ < 2; ++n_)                          \
    _Pragma("unroll") for (int kk_ = 0; kk_ < 2; ++kk_) {                     \
        int rb_ = wc * 64 + (NH) * 32 + n_ * 16 + lrow;                       \
        DST[n_][kk_] = *(const short8*)(ldsBp + rb_ * 128 +                   \
            ((kk_ * 64 + lgrp * 16) ^ ((rb_ & 7) << 4))); }

#define MFMA16(AF, BF, MB, NB)                                                \
    __builtin_amdgcn_s_setprio(1);                                            \
    _Pragma("unroll") for (int m_ = 0; m_ < 4; ++m_)                          \
    _Pragma("unroll") for (int n_ = 0; n_ < 2; ++n_)                          \
    _Pragma("unroll") for (int kk_ = 0; kk_ < 2; ++kk_)                       \
        acc[(MB) + m_][(NB) + n_] = __builtin_amdgcn_mfma_f32_16x16x32_bf16(  \
            AF[m_][kk_], BF[n_][kk_], acc[(MB) + m_][(NB) + n_], 0, 0, 0);    \
    __builtin_amdgcn_s_setprio(0);

#define SBAR()                                                                \
    __builtin_amdgcn_sched_barrier(0);                                        \
    __builtin_amdgcn_s_barrier();                                             \
    __builtin_amdgcn_sched_barrier(0);

    // Prologue: stage halves 0..5 (tile0 B0,B1,A0,A1 + tile1 B0,B1).
#pragma unroll
    for (int s = 0; s < 6; ++s) STAGE_HALF(s);

    for (int t = 0; t < NT; ++t) {
        const int p = t & 1;
        const unsigned char* ldsAp = lds + p * 32768;
        const unsigned char* ldsBp = lds + 65536 + p * 32768;
        short8 afa[4][2], afb[4][2], bfa[2][2], bfb[2][2];

        // ---- P0: quadrant (mh0, nh0) ----
        STAGE_HALF(4 * t + 6);
        if (t < NT - 1) { asm volatile("s_waitcnt vmcnt(6)" ::: "memory"); }
        else            { asm volatile("s_waitcnt vmcnt(0)" ::: "memory"); }
        SBAR();                       // tile t fully landed for all waves
        LOAD_A(afa, 0);
        LOAD_B(bfa, 0);
        MFMA16(afa, bfa, 0, 0);
        SBAR();
        // ---- P1: quadrant (mh0, nh1) ----
        STAGE_HALF(4 * t + 7);
        LOAD_B(bfb, 1);
        MFMA16(afa, bfb, 0, 2);
        SBAR();                       // B halves of tile t dead
        // ---- P2: quadrant (mh1, nh0) ----
        STAGE_HALF(4 * t + 8);
        LOAD_A(afb, 1);
        MFMA16(afb, bfa, 4, 0);
        SBAR();                       // A halves of tile t dead
        // ---- P3: quadrant (mh1, nh1) ----
        STAGE_HALF(4 * t + 9);
        MFMA16(afb, bfb, 4, 2);
        SBAR();
    }

    // Epilogue: per token row, (max, sumexp) over this wave's 64 vocab cols.
    // C/D layout: col = lane&15, row = (lane>>4)*4 + reg  [m89/m91]
    const int nb = (tile_n >> 6) + wc;
#pragma unroll
    for (int mi = 0; mi < 8; ++mi) {
#pragma unroll
        for (int r = 0; r < 4; ++r) {
            float v0 = acc[mi][0][r], v1 = acc[mi][1][r], v2 = acc[mi][2][r], v3 = acc[mi][3][r];
            float mx = fmaxf(fmaxf(v0, v1), fmaxf(v2, v3));
#pragma unroll
            for (int d = 1; d < 16; d <<= 1) mx = fmaxf(mx, __shfl_xor(mx, d, 64));
            float s = __expf(v0 - mx) + __expf(v1 - mx) + __expf(v2 - mx) + __expf(v3 - mx);
#pragma unroll
            for (int d = 1; d < 16; d <<= 1) s += __shfl_xor(s, d, 64);
            if (lrow == 0) {
                int rowg = tile_m + wr * 128 + mi * 16 + lgrp * 4 + r;
                part[(size_t)rowg * NPB + nb] = make_float2(mx, s);
            }
        }
    }
}

// ---------------- fallback: round-1 fused fp32 reg-staged GEMM (128²) -------
__global__ __launch_bounds__(256) void kto_logits_lse(
    const float* __restrict__ X, const float* __restrict__ Wt,
    float2* __restrict__ part)
{
    __shared__ __align__(16) unsigned char ldsf[(128 + 128) * BK * 2];
    unsigned char* ldsA = ldsf;
    unsigned char* ldsB = ldsf + 128 * BK * 2;

    const int tid    = threadIdx.x;
    const int tile_m = blockIdx.x * 128;
    const int tile_n = blockIdx.y * 128;
    const int srow   = tid >> 1;
    const int shalf  = tid & 1;
    const int lane   = tid & 63;
    const int wave   = tid >> 6;
    const int wm     = (wave >> 1) * 64;
    const int wn     = (wave & 1) * 64;
    const int lrow   = lane & 15;
    const int lgrp   = lane >> 4;

    f32x4 acc[4][4];
#pragma unroll
    for (int i = 0; i < 4; ++i)
#pragma unroll
        for (int j = 0; j < 4; ++j) acc[i][j] = f32x4{0.f, 0.f, 0.f, 0.f};

    const float4* gA = (const float4*)(X  + (size_t)(tile_m + srow) * HH) + shalf * 8;
    const float4* gB = (const float4*)(Wt + (size_t)(tile_n + srow) * HH) + shalf * 8;
    const int swzf = (srow & 7) << 4;

    for (int k0 = 0; k0 < HH; k0 += BK) {
        float4 a[8], b[8];
#pragma unroll
        for (int j = 0; j < 8; ++j) a[j] = gA[j];
#pragma unroll
        for (int j = 0; j < 8; ++j) b[j] = gB[j];
        gA += BK / 4; gB += BK / 4;

        __syncthreads();
#pragma unroll
        for (int j = 0; j < 4; ++j) {
            uint2 lo = pack4(a[2*j]), hi = pack4(a[2*j+1]);
            uint4 qa = make_uint4(lo.x, lo.y, hi.x, hi.y);
            lo = pack4(b[2*j]); hi = pack4(b[2*j+1]);
            uint4 qb = make_uint4(lo.x, lo.y, hi.x, hi.y);
            int kb = shalf * 64 + 16 * j;
            *(uint4*)(ldsA + srow * 128 + (kb ^ swzf)) = qa;
            *(uint4*)(ldsB + srow * 128 + (kb ^ swzf)) = qb;
        }
        __syncthreads();

#pragma unroll
        for (int kk = 0; kk < 2; ++kk) {
            short8 af[4], bf[4];
#pragma unroll
            for (int mi = 0; mi < 4; ++mi) {
                int r = wm + mi * 16 + lrow;
                af[mi] = *(const short8*)(ldsA + r * 128 + ((kk * 64 + lgrp * 16) ^ ((r & 7) << 4)));
            }
#pragma unroll
            for (int ni = 0; ni < 4; ++ni) {
                int r = wn + ni * 16 + lrow;
                bf[ni] = *(const short8*)(ldsB + r * 128 + ((kk * 64 + lgrp * 16) ^ ((r & 7) << 4)));
            }
#pragma unroll
            for (int mi = 0; mi < 4; ++mi)
#pragma unroll
                for (int ni = 0; ni < 4; ++ni)
                    acc[mi][ni] = __builtin_amdgcn_mfma_f32_16x16x32_bf16(af[mi], bf[ni], acc[mi][ni], 0, 0, 0);
        }
    }

    const int nb = blockIdx.y * 2 + (wave & 1);
#pragma unroll
    for (int mi = 0; mi < 4; ++mi) {
#pragma unroll
        for (int r = 0; r < 4; ++r) {
            float v0 = acc[mi][0][r], v1 = acc[mi][1][r], v2 = acc[mi][2][r], v3 = acc[mi][3][r];
            float mx = fmaxf(fmaxf(v0, v1), fmaxf(v2, v3));
#pragma unroll
            for (int d = 1; d < 16; d <<= 1) mx = fmaxf(mx, __shfl_xor(mx, d, 64));
            float s = __expf(v0 - mx) + __expf(v1 - mx) + __expf(v2 - mx) + __expf(v3 - mx);
#pragma unroll
            for (int d = 1; d < 16; d <<= 1) s += __shfl_xor(s, d, 64);
            if (lrow == 0) {
                int rowg = tile_m + wm + mi * 16 + lgrp * 4 + r;
                part[(size_t)rowg * NPB + nb] = make_float2(mx, s);
            }
        }
    }
}

// ---------------- target logit per token (fp32 exact) -----------------------
__global__ __launch_bounds__(256) void kto_target(
    const float* __restrict__ X, const float* __restrict__ RX,
    const float* __restrict__ W, const float* __restrict__ RW,
    const int* __restrict__ Y,
    float* __restrict__ tgtP, float* __restrict__ tgtR)
{
    __shared__ float red[2][4];
    const int t = blockIdx.x;
    int yt = Y[t]; yt = yt < 0 ? 0 : (yt > VV - 1 ? VV - 1 : yt);
    const float4* x4  = (const float4*)(X  + (size_t)t  * HH);
    const float4* rx4 = (const float4*)(RX + (size_t)t  * HH);
    const float4* w4  = (const float4*)(W  + (size_t)yt * HH);
    const float4* rw4 = (const float4*)(RW + (size_t)yt * HH);
    float sp = 0.f, sr = 0.f;
    for (int i = threadIdx.x; i < HH / 4; i += 256) {
        float4 a = x4[i],  w = w4[i];
        sp += a.x * w.x + a.y * w.y + a.z * w.z + a.w * w.w;
        float4 bq = rx4[i], rw = rw4[i];
        sr += bq.x * rw.x + bq.y * rw.y + bq.z * rw.z + bq.w * rw.w;
    }
#pragma unroll
    for (int d = 1; d < 64; d <<= 1) { sp += __shfl_xor(sp, d, 64); sr += __shfl_xor(sr, d, 64); }
    int wv = threadIdx.x >> 6, ln = threadIdx.x & 63;
    if (ln == 0) { red[0][wv] = sp; red[1][wv] = sr; }
    __syncthreads();
    if (threadIdx.x == 0) {
        tgtP[t] = red[0][0] + red[0][1] + red[0][2] + red[0][3];
        tgtR[t] = red[1][0] + red[1][1] + red[1][2] + red[1][3];
    }
}

__device__ inline float2 mrg(float2 a, float2 b) {
    if (b.x == -INFINITY) return a;
    if (a.x == -INFINITY) return b;
    if (a.x >= b.x) { a.y += b.y * __expf(b.x - a.x); return a; }
    b.y += a.y * __expf(a.x - b.x); return b;
}

__global__ __launch_bounds__(256) void kto_lse_combine(
    const float2* __restrict__ partP, const float2* __restrict__ partR,
    const float* __restrict__ tgtP, const float* __restrict__ tgtR,
    float* __restrict__ tokP, float* __restrict__ tokR)
{
    __shared__ float2 redP[4], redR[4];
    const int t = blockIdx.x;
    float2 ap = make_float2(-INFINITY, 0.f), ar = ap;
    for (int i = threadIdx.x; i < NPB; i += 256) {
        ap = mrg(ap, partP[(size_t)t * NPB + i]);
        ar = mrg(ar, partR[(size_t)t * NPB + i]);
    }
#pragma unroll
    for (int d = 1; d < 64; d <<= 1) {
        float2 o;
        o.x = __shfl_xor(ap.x, d, 64); o.y = __shfl_xor(ap.y, d, 64); ap = mrg(ap, o);
        o.x = __shfl_xor(ar.x, d, 64); o.y = __shfl_xor(ar.y, d, 64); ar = mrg(ar, o);
    }
    int wv = threadIdx.x >> 6, ln = threadIdx.x & 63;
    if (ln == 0) { redP[wv] = ap; redR[wv] = ar; }
    __syncthreads();
    if (threadIdx.x == 0) {
        float2 p = mrg(mrg(redP[0], redP[1]), mrg(redP[2], redP[3]));
        float2 r = mrg(mrg(redR[0], redR[1]), mrg(redR[2], redR[3]));
        tokP[t] = tgtP[t] - (p.x + logf(p.y));
        tokR[t] = tgtR[t] - (r.x + logf(r.y));
    }
}

__global__ __launch_bounds__(1024) void kto_final(
    const float* __restrict__ tokP, const float* __restrict__ tokR,
    const int* __restrict__ Y, const unsigned char* __restrict__ pref,
    float* __restrict__ out)
{
    __shared__ float red[6][16];
    const int t = threadIdx.x;  // 0..1023
    float m0 = (Y[t]      != -100) ? 1.f : 0.f;
    float m1 = (Y[TT + t] != -100) ? 1.f : 0.f;
    float v[6];
    v[0] = m0 * tokP[t];       v[1] = m0 * tokR[t];       v[2] = m0;
    v[3] = m1 * tokP[TT + t];  v[4] = m1 * tokR[TT + t];  v[5] = m1;
#pragma unroll
    for (int d = 1; d < 64; d <<= 1)
#pragma unroll
        for (int j = 0; j < 6; ++j) v[j] += __shfl_xor(v[j], d, 64);
    int wv = threadIdx.x >> 6, ln = threadIdx.x & 63;
    if (ln == 0)
#pragma unroll
        for (int j = 0; j < 6; ++j) red[j][wv] = v[j];
    __syncthreads();
    if (t == 0) {
        float s[6];
#pragma unroll
        for (int j = 0; j < 6; ++j) { s[j] = 0.f; for (int w = 0; w < 16; ++w) s[j] += red[j][w]; }
        bool byteStorage = ((pref[1] | pref[2] | pref[3]) != 0) || (pref[4] > 1) ||
                           ((pref[5] | pref[6] | pref[7]) != 0);
        int l0, l1;
        if (byteStorage) { l0 = pref[0]; l1 = pref[1]; }
        else { l0 = ((const int*)pref)[0]; l1 = ((const int*)pref)[1]; }
        float pl0 = s[0] / fmaxf(s[2], 1.f);
        float rl0 = s[1] / fmaxf(s[2], 1.f);
        float pl1 = s[3] / fmaxf(s[5], 1.f);
        float rl1 = s[4] / fmaxf(s[5], 1.f);
        float lr0 = pl0 - rl0, lr1 = pl1 - rl1;
        float mu0 = l0 ? 1.f : -1.f;
        float mu1 = l1 ? 1.f : -1.f;
        float loss0 = 1.f - 1.f / (1.f + expf(-BETA_ * lr0 * mu0));
        float loss1 = 1.f - 1.f / (1.f + expf(-BETA_ * lr1 * mu1));
        out[0] = 0.5f * (loss0 + loss1);
    }
}

extern "C" void kernel_launch(void* const* d_in, const int* in_sizes, int n_in,
                              void* d_out, int out_size, void* d_ws, size_t ws_size,
                              hipStream_t stream) {
    const float* X  = (const float*)d_in[0];
    const float* RX = (const float*)d_in[1];
    const int*   Y  = (const int*)d_in[2];
    const unsigned char* PL = (const unsigned char*)d_in[3];
    const float* W  = (const float*)d_in[4];
    const float* RW = (const float*)d_in[5];
    float* out = (float*)d_out;

    // ws layout
    char* p = (char*)d_ws;
    float2* partP = (float2*)p;                 p += (size_t)MM * NPB * sizeof(float2);
    float2* partR = (float2*)p;                 p += (size_t)MM * NPB * sizeof(float2);
    float*  tgtP  = (float*)p;                  p += MM * sizeof(float);
    float*  tgtR  = (float*)p;                  p += MM * sizeof(float);
    float*  tokP  = (float*)p;                  p += MM * sizeof(float);
    float*  tokR  = (float*)p;                  p += MM * sizeof(float);
    unsigned short* Xbf  = (unsigned short*)p;  p += (size_t)MM * HH * 2;
    unsigned short* RXbf = (unsigned short*)p;  p += (size_t)MM * HH * 2;
    unsigned short* Wbf  = (unsigned short*)p;  p += (size_t)VV * HH * 2;
    const size_t need = (size_t)(p - (char*)d_ws);

    if (ws_size >= need) {
        // fast path: pre-convert to bf16, then 8-phase 256² GEMMs.
        dim3 ggrid(MM / BM, VV / BN);  // (8, 125)
        conv_bf16<<<512,  256, 0, stream>>>(X,  Xbf,  (int)((size_t)MM * HH / 8));
        conv_bf16<<<512,  256, 0, stream>>>(RX, RXbf, (int)((size_t)MM * HH / 8));
        conv_bf16<<<2048, 256, 0, stream>>>(W,  Wbf,  (int)((size_t)VV * HH / 8));
        kto_logits_lse_bf16_8p<<<ggrid, 512, 0, stream>>>(Xbf, Wbf, partP);
        conv_bf16<<<2048, 256, 0, stream>>>(RW, Wbf,  (int)((size_t)VV * HH / 8));
        kto_logits_lse_bf16_8p<<<ggrid, 512, 0, stream>>>(RXbf, Wbf, partR);
    } else {
        // fallback: fused fp32 reg-staged path (round-1, known-correct)
        dim3 fgrid(MM / 128, VV / 128);
        kto_logits_lse<<<fgrid, 256, 0, stream>>>(X,  W,  partP);
        kto_logits_lse<<<fgrid, 256, 0, stream>>>(RX, RW, partR);
    }
    kto_target<<<MM, 256, 0, stream>>>(X, RX, W, RW, Y, tgtP, tgtR);
    kto_lse_combine<<<MM, 256, 0, stream>>>(partP, partR, tgtP, tgtR, tokP, tokR);
    kto_final<<<1, 1024, 0, stream>>>(tokP, tokR, Y, PL, out);
}